// Round 1
// baseline (1148.553 us; speedup 1.0000x reference)
//
#include <hip/hip_runtime.h>

// GridMatch: A=8, B=8, N=2048, grid 640x480 per (a,b) image.
#define AD 8
#define BD 8
#define NP 2048
#define MPTS (AD*BD*NP)            // 131072 points
#define GRID_CAP 19660800LL        // 8*8*640*480 cells
#define NBLK 1024                  // blocks for count/emit passes

// Grids store (point_id + 1); 0 == empty. Zero-initialized at module load;
// k_clear restores zeros at the end of every call (deterministic).
__device__ int g_grid0[19660800];
__device__ int g_grid1[19660800];
__device__ int g_cnt[NBLK];
__device__ int g_off[NBLK];

// ---------------- default fill for all M output rows ----------------
__global__ void k_fill(float* __restrict__ out) {
  int r = blockIdx.x * blockDim.x + threadIdx.x;
  if (r >= MPTS) return;
  out[2*r]            = 0.f; out[2*r+1]            = 0.f;  // src_coord_m
  out[2*MPTS + 2*r]   = 0.f; out[2*MPTS + 2*r+1]   = 0.f;  // dst_coord_m
  out[4*MPTS + 2*r]   = -1.f; out[4*MPTS + 2*r+1]  = -1.f; // src_bn
  out[6*MPTS + 2*r]   = -1.f; out[6*MPTS + 2*r+1]  = -1.f; // dst_an
  out[8*MPTS + r]     = 0.f;                               // valid
}

// ---------------- scatter: atomicMax(id+1) into both grids ----------------
__global__ void k_scatter(const float* __restrict__ ps, const float* __restrict__ pd,
                          const int* __restrict__ ph, const int* __restrict__ pw,
                          const int* __restrict__ pg) {
  int id = blockIdx.x * blockDim.x + threadIdx.x;
  if (id >= MPTS) return;
  int h = *ph, w = *pw, gs = *pg;
  int gh = h * gs, gw = w * gs;
  float sx = (float)((gw - 1) * 0.5);
  float sy = (float)((gh - 1) * 0.5);
  int ab = id / NP;  // a*B + b

  float px = ps[2*id], py = ps[2*id+1];
  if (px >= -1.f && px <= 1.f && py >= -1.f && py <= 1.f) {
    long long c = ((long long)(ab * gw + (int)((px + 1.f) * sx))) * gh
                  + (int)((py + 1.f) * sy);
    if (c >= 0 && c < GRID_CAP) atomicMax(&g_grid0[c], id + 1);
  }
  px = pd[2*id]; py = pd[2*id+1];
  if (px >= -1.f && px <= 1.f && py >= -1.f && py <= 1.f) {
    long long c = ((long long)(ab * gw + (int)((px + 1.f) * sx))) * gh
                  + (int)((py + 1.f) * sy);
    if (c >= 0 && c < GRID_CAP) atomicMax(&g_grid1[c], id + 1);
  }
}

// ---------------- count matches per block (contiguous cell ranges) ----------------
__global__ void k_count(const int* __restrict__ ph, const int* __restrict__ pw,
                        const int* __restrict__ pg) {
  int h = *ph, w = *pw, gs = *pg;
  long long C = (long long)AD * BD * (long long)(w * gs) * (long long)(h * gs);
  if (C > GRID_CAP) C = GRID_CAP;
  long long pb = (C + NBLK - 1) / NBLK;
  long long bs = (long long)blockIdx.x * pb;
  long long be = bs + pb; if (be > C) be = C;
  long long ipt = (pb + blockDim.x - 1) / blockDim.x;
  long long ts = bs + (long long)threadIdx.x * ipt;
  long long te = ts + ipt; if (te > be) te = be;

  int cnt = 0;
  for (long long c = ts; c < te; ++c)
    cnt += (int)((g_grid0[c] != 0) & (g_grid1[c] != 0));

  __shared__ int sm[256];
  sm[threadIdx.x] = cnt;
  __syncthreads();
  for (int off = 128; off > 0; off >>= 1) {
    if (threadIdx.x < off) sm[threadIdx.x] += sm[threadIdx.x + off];
    __syncthreads();
  }
  if (threadIdx.x == 0) g_cnt[blockIdx.x] = sm[0];
}

// ---------------- exclusive scan of the NBLK block counts ----------------
__global__ void k_scan() {
  __shared__ int sm[NBLK];
  int v = g_cnt[threadIdx.x];
  sm[threadIdx.x] = v;
  for (int off = 1; off < NBLK; off <<= 1) {
    __syncthreads();
    int t = (threadIdx.x >= (unsigned)off) ? sm[threadIdx.x - off] : 0;
    __syncthreads();
    sm[threadIdx.x] += t;
  }
  __syncthreads();
  g_off[threadIdx.x] = sm[threadIdx.x] - v;
}

// ---------------- emit matched rows at stable compacted ranks ----------------
__global__ void k_emit(const float* __restrict__ ps, const float* __restrict__ pd,
                       float* __restrict__ out,
                       const int* __restrict__ ph, const int* __restrict__ pw,
                       const int* __restrict__ pg) {
  int h = *ph, w = *pw, gs = *pg;
  int gh = h * gs, gw = w * gs;
  long long C = (long long)AD * BD * (long long)gw * (long long)gh;
  if (C > GRID_CAP) C = GRID_CAP;
  long long pb = (C + NBLK - 1) / NBLK;
  long long bs = (long long)blockIdx.x * pb;
  long long be = bs + pb; if (be > C) be = C;
  long long ipt = (pb + blockDim.x - 1) / blockDim.x;
  long long ts = bs + (long long)threadIdx.x * ipt;
  long long te = ts + ipt; if (te > be) te = be;

  // pass 1: per-thread match count
  int cnt = 0;
  for (long long c = ts; c < te; ++c)
    cnt += (int)((g_grid0[c] != 0) & (g_grid1[c] != 0));

  // block-wide exclusive scan (stable: thread t owns contiguous cells)
  __shared__ int sm[256];
  sm[threadIdx.x] = cnt;
  for (int off = 1; off < 256; off <<= 1) {
    __syncthreads();
    int t = (threadIdx.x >= (unsigned)off) ? sm[threadIdx.x - off] : 0;
    __syncthreads();
    sm[threadIdx.x] += t;
  }
  __syncthreads();
  int rank = g_off[blockIdx.x] + (sm[threadIdx.x] - cnt);

  float sx = (float)((gw - 1) * 0.5);
  float sy = (float)((gh - 1) * 0.5);
  float fx = (float)((double)(h - 1) / (double)(gh - 1));  // pairs with x (faithful)
  float fy = (float)((double)(w - 1) / (double)(gw - 1));

  float* out0 = out;               // src_coord_m [M,2]
  float* out1 = out + 2*MPTS;      // dst_coord_m [M,2]
  float* out2 = out + 4*MPTS;      // src_bn      [M,2]
  float* out3 = out + 6*MPTS;      // dst_an      [M,2]
  float* out4 = out + 8*MPTS;      // valid       [M]

  // pass 2: write matches in cell order
  for (long long c = ts; c < te; ++c) {
    int v0 = g_grid0[c], v1 = g_grid1[c];
    if (v0 != 0 && v1 != 0) {
      int s = v0 - 1, d = v1 - 1;
      float spx = ps[2*s], spy = ps[2*s+1];
      out0[2*rank]   = (spx + 1.f) * sx * fx;
      out0[2*rank+1] = (spy + 1.f) * sy * fy;
      float dpx = pd[2*d], dpy = pd[2*d+1];
      out1[2*rank]   = (dpx + 1.f) * sx * fx;
      out1[2*rank+1] = (dpy + 1.f) * sy * fy;
      out2[2*rank]   = (float)((s / NP) % BD);
      out2[2*rank+1] = (float)(s % NP);
      out3[2*rank]   = (float)(d / (BD * NP));
      out3[2*rank+1] = (float)(d % NP);
      out4[rank]     = 1.f;
      ++rank;
    }
  }
}

// ---------------- clear touched cells back to 0 (restore invariant) ----------------
__global__ void k_clear(const float* __restrict__ ps, const float* __restrict__ pd,
                        const int* __restrict__ ph, const int* __restrict__ pw,
                        const int* __restrict__ pg) {
  int id = blockIdx.x * blockDim.x + threadIdx.x;
  if (id >= MPTS) return;
  int h = *ph, w = *pw, gs = *pg;
  int gh = h * gs, gw = w * gs;
  float sx = (float)((gw - 1) * 0.5);
  float sy = (float)((gh - 1) * 0.5);
  int ab = id / NP;

  float px = ps[2*id], py = ps[2*id+1];
  if (px >= -1.f && px <= 1.f && py >= -1.f && py <= 1.f) {
    long long c = ((long long)(ab * gw + (int)((px + 1.f) * sx))) * gh
                  + (int)((py + 1.f) * sy);
    if (c >= 0 && c < GRID_CAP) g_grid0[c] = 0;
  }
  px = pd[2*id]; py = pd[2*id+1];
  if (px >= -1.f && px <= 1.f && py >= -1.f && py <= 1.f) {
    long long c = ((long long)(ab * gw + (int)((px + 1.f) * sx))) * gh
                  + (int)((py + 1.f) * sy);
    if (c >= 0 && c < GRID_CAP) g_grid1[c] = 0;
  }
}

extern "C" void kernel_launch(void* const* d_in, const int* in_sizes, int n_in,
                              void* d_out, int out_size, void* d_ws, size_t ws_size,
                              hipStream_t stream) {
  const float* ps = (const float*)d_in[0];
  const float* pd = (const float*)d_in[1];
  const int* ph = (const int*)d_in[2];
  const int* pw = (const int*)d_in[3];
  const int* pg = (const int*)d_in[4];
  float* out = (float*)d_out;

  k_fill   <<<MPTS/256, 256, 0, stream>>>(out);
  k_scatter<<<MPTS/256, 256, 0, stream>>>(ps, pd, ph, pw, pg);
  k_count  <<<NBLK,     256, 0, stream>>>(ph, pw, pg);
  k_scan   <<<1,       NBLK, 0, stream>>>();
  k_emit   <<<NBLK,     256, 0, stream>>>(ps, pd, out, ph, pw, pg);
  k_clear  <<<MPTS/256, 256, 0, stream>>>(ps, pd, ph, pw, pg);
}

// Round 2
// 31.504 us; speedup vs baseline: 36.4569x; 36.4569x over previous
//
#include <hip/hip_runtime.h>

// GridMatch: A=8, B=8, N=2048, grid 640x480 per (a,b) image.
#define AD 8
#define BD 8
#define NP 2048
#define MPTS (AD*BD*NP)            // 131072 points
#define GRID_CAP 19660800LL        // 8*8*640*480 cells

// Grids store (point_id + 1); 0 == empty. Zero-initialized at module load;
// k_clear restores zeros at the end of every call (deterministic).
__device__ int g_grid0[19660800];
__device__ int g_grid1[19660800];
__device__ int g_nm;               // match count (zeroed in k_fill each call)
__device__ int g_cell[MPTS];       // unordered match records
__device__ int g_src[MPTS];
__device__ int g_dst[MPTS];

// ---------------- default fill for all M output rows + zero match counter ----
__global__ void k_fill(float* __restrict__ out) {
  int r = blockIdx.x * blockDim.x + threadIdx.x;
  if (r == 0) g_nm = 0;
  if (r >= MPTS) return;
  float2* o01 = (float2*)out;
  o01[r]          = make_float2(0.f, 0.f);    // src_coord_m
  o01[MPTS + r]   = make_float2(0.f, 0.f);    // dst_coord_m
  o01[2*MPTS + r] = make_float2(-1.f, -1.f);  // src_bn
  o01[3*MPTS + r] = make_float2(-1.f, -1.f);  // dst_an
  out[8*MPTS + r] = 0.f;                      // valid
}

// ---------------- scatter: atomicMax(id+1) into both grids ----------------
__global__ void k_scatter(const float* __restrict__ ps, const float* __restrict__ pd,
                          const int* __restrict__ ph, const int* __restrict__ pw,
                          const int* __restrict__ pg) {
  int id = blockIdx.x * blockDim.x + threadIdx.x;
  if (id >= MPTS) return;
  int h = *ph, w = *pw, gs = *pg;
  int gh = h * gs, gw = w * gs;
  float sx = (float)((gw - 1) * 0.5);
  float sy = (float)((gh - 1) * 0.5);
  int ab = id / NP;  // a*B + b

  float px = ps[2*id], py = ps[2*id+1];
  if (px >= -1.f && px <= 1.f && py >= -1.f && py <= 1.f) {
    long long c = ((long long)(ab * gw + (int)((px + 1.f) * sx))) * gh
                  + (int)((py + 1.f) * sy);
    if (c >= 0 && c < GRID_CAP) atomicMax(&g_grid0[c], id + 1);
  }
  px = pd[2*id]; py = pd[2*id+1];
  if (px >= -1.f && px <= 1.f && py >= -1.f && py <= 1.f) {
    long long c = ((long long)(ab * gw + (int)((px + 1.f) * sx))) * gh
                  + (int)((py + 1.f) * sy);
    if (c >= 0 && c < GRID_CAP) atomicMax(&g_grid1[c], id + 1);
  }
}

// ---------------- collect: winning src points whose cell also has a dst ------
__global__ void k_collect(const float* __restrict__ ps,
                          const int* __restrict__ ph, const int* __restrict__ pw,
                          const int* __restrict__ pg) {
  int id = blockIdx.x * blockDim.x + threadIdx.x;
  if (id >= MPTS) return;
  int h = *ph, w = *pw, gs = *pg;
  int gh = h * gs, gw = w * gs;
  float sx = (float)((gw - 1) * 0.5);
  float sy = (float)((gh - 1) * 0.5);
  int ab = id / NP;

  float px = ps[2*id], py = ps[2*id+1];
  if (!(px >= -1.f && px <= 1.f && py >= -1.f && py <= 1.f)) return;
  long long c = ((long long)(ab * gw + (int)((px + 1.f) * sx))) * gh
                + (int)((py + 1.f) * sy);
  if (c < 0 || c >= GRID_CAP) return;
  if (g_grid0[c] != id + 1) return;     // not the max-id (last-write-wins) owner
  int v1 = g_grid1[c];
  if (v1 == 0) return;                  // no dst point in this cell
  int slot = atomicAdd(&g_nm, 1);
  g_cell[slot] = (int)c;
  g_src[slot]  = id;
  g_dst[slot]  = v1 - 1;
}

// ---------------- sort records by cell (row-major rank) and emit -------------
__global__ void k_sortemit(const float* __restrict__ ps, const float* __restrict__ pd,
                           float* __restrict__ out,
                           const int* __restrict__ ph, const int* __restrict__ pw,
                           const int* __restrict__ pg) {
  int n = g_nm; if (n > MPTS) n = MPTS;
  int h = *ph, w = *pw, gs = *pg;
  int gh = h * gs, gw = w * gs;
  float sx = (float)((gw - 1) * 0.5);
  float sy = (float)((gh - 1) * 0.5);
  float fx = (float)((double)(h - 1) / (double)(gh - 1));  // pairs with x (faithful)
  float fy = (float)((double)(w - 1) / (double)(gw - 1));

  float* out0 = out;               // src_coord_m [M,2]
  float* out1 = out + 2*MPTS;      // dst_coord_m [M,2]
  float* out2 = out + 4*MPTS;      // src_bn      [M,2]
  float* out3 = out + 6*MPTS;      // dst_an      [M,2]
  float* out4 = out + 8*MPTS;      // valid       [M]

  for (int i = threadIdx.x; i < n; i += blockDim.x) {
    int ci = g_cell[i];
    int rank = 0;
    for (int j = 0; j < n; ++j) rank += (int)(g_cell[j] < ci);  // cells unique
    int s = g_src[i], d = g_dst[i];
    float spx = ps[2*s], spy = ps[2*s+1];
    out0[2*rank]   = (spx + 1.f) * sx * fx;
    out0[2*rank+1] = (spy + 1.f) * sy * fy;
    float dpx = pd[2*d], dpy = pd[2*d+1];
    out1[2*rank]   = (dpx + 1.f) * sx * fx;
    out1[2*rank+1] = (dpy + 1.f) * sy * fy;
    out2[2*rank]   = (float)((s / NP) % BD);
    out2[2*rank+1] = (float)(s % NP);
    out3[2*rank]   = (float)(d / (BD * NP));
    out3[2*rank+1] = (float)(d % NP);
    out4[rank]     = 1.f;
  }
}

// ---------------- clear touched cells back to 0 (restore invariant) ----------
__global__ void k_clear(const float* __restrict__ ps, const float* __restrict__ pd,
                        const int* __restrict__ ph, const int* __restrict__ pw,
                        const int* __restrict__ pg) {
  int id = blockIdx.x * blockDim.x + threadIdx.x;
  if (id >= MPTS) return;
  int h = *ph, w = *pw, gs = *pg;
  int gh = h * gs, gw = w * gs;
  float sx = (float)((gw - 1) * 0.5);
  float sy = (float)((gh - 1) * 0.5);
  int ab = id / NP;

  float px = ps[2*id], py = ps[2*id+1];
  if (px >= -1.f && px <= 1.f && py >= -1.f && py <= 1.f) {
    long long c = ((long long)(ab * gw + (int)((px + 1.f) * sx))) * gh
                  + (int)((py + 1.f) * sy);
    if (c >= 0 && c < GRID_CAP) g_grid0[c] = 0;
  }
  px = pd[2*id]; py = pd[2*id+1];
  if (px >= -1.f && px <= 1.f && py >= -1.f && py <= 1.f) {
    long long c = ((long long)(ab * gw + (int)((px + 1.f) * sx))) * gh
                  + (int)((py + 1.f) * sy);
    if (c >= 0 && c < GRID_CAP) g_grid1[c] = 0;
  }
}

extern "C" void kernel_launch(void* const* d_in, const int* in_sizes, int n_in,
                              void* d_out, int out_size, void* d_ws, size_t ws_size,
                              hipStream_t stream) {
  const float* ps = (const float*)d_in[0];
  const float* pd = (const float*)d_in[1];
  const int* ph = (const int*)d_in[2];
  const int* pw = (const int*)d_in[3];
  const int* pg = (const int*)d_in[4];
  float* out = (float*)d_out;

  k_fill    <<<MPTS/256, 256, 0, stream>>>(out);
  k_scatter <<<MPTS/256, 256, 0, stream>>>(ps, pd, ph, pw, pg);
  k_collect <<<MPTS/256, 256, 0, stream>>>(ps, ph, pw, pg);
  k_sortemit<<<1,        256, 0, stream>>>(ps, pd, out, ph, pw, pg);
  k_clear   <<<MPTS/256, 256, 0, stream>>>(ps, pd, ph, pw, pg);
}